// Round 1
// baseline (312.413 us; speedup 1.0000x reference)
//
#include <hip/hip_runtime.h>
#include <hip/hip_bf16.h>

#define N_NODES 50000
#define N_EDGES_REF 800000
#define IN_FEAT 128
#define N_HEADS 4
#define OUT_FEAT 16
#define HF 64  // N_HEADS * OUT_FEAT
#define NEG_SLOPE 0.2f

// ---------------------------------------------------------------------------
// Kernel 1: h = x @ W  (50000x128 @ 128x64), fused e_src/e_dst reductions.
// One block handles 16 nodes. LDS: W 32KB + x-tile 8KB + h-tile 4KB = 44KB.
// ---------------------------------------------------------------------------
__global__ __launch_bounds__(256) void k_gemm(
    const float* __restrict__ x, const float* __restrict__ W,
    const float* __restrict__ a, float* __restrict__ h,
    float* __restrict__ e_src, float* __restrict__ e_dst, int n_nodes) {
  __shared__ float sW[IN_FEAT][HF];   // W[k][c]
  __shared__ float sx[16][IN_FEAT];
  __shared__ float sh[16][HF];
  const int t = threadIdx.x;
  const int nb = blockIdx.x * 16;

  // Load W (row-major 128x64) — coalesced.
  for (int i = t; i < IN_FEAT * HF; i += 256) sW[i >> 6][i & 63] = W[i];
  // Load 16-node x tile — coalesced along k.
  for (int i = t; i < 16 * IN_FEAT; i += 256) {
    int n = i >> 7, k = i & 127;
    int gn = nb + n;
    sx[n][k] = (gn < n_nodes) ? x[(size_t)gn * IN_FEAT + k] : 0.f;
  }
  __syncthreads();

  // 16 nodes x 64 feats = 1024 outputs; 256 threads -> 4 each.
  const int c = t & 63, n0 = t >> 6;
  for (int rep = 0; rep < 4; ++rep) {
    int n = n0 + rep * 4;
    float acc = 0.f;
#pragma unroll
    for (int k = 0; k < IN_FEAT; ++k) acc = fmaf(sx[n][k], sW[k][c], acc);
    sh[n][c] = acc;
    int gn = nb + n;
    if (gn < n_nodes) h[(size_t)gn * HF + c] = acc;
  }
  __syncthreads();

  // e_src/e_dst: 16 nodes x 4 heads = 64 entries.
  if (t < 64) {
    int n = t >> 2, hd = t & 3;
    int gn = nb + n;
    if (gn < n_nodes) {
      float es = 0.f, ed = 0.f;
#pragma unroll
      for (int f = 0; f < OUT_FEAT; ++f) {
        float hv = sh[n][hd * OUT_FEAT + f];
        es = fmaf(hv, a[hd * 2 * OUT_FEAT + f], es);
        ed = fmaf(hv, a[hd * 2 * OUT_FEAT + OUT_FEAT + f], ed);
      }
      e_src[gn * N_HEADS + hd] = es;
      e_dst[gn * N_HEADS + hd] = ed;
    }
  }
}

// ---------------------------------------------------------------------------
// Kernel 2: per-edge leaky-relu + softmax over 4 heads -> alpha[e][4]
// ---------------------------------------------------------------------------
__global__ __launch_bounds__(256) void k_alpha(
    const int* __restrict__ src, const int* __restrict__ dst,
    const float* __restrict__ e_src, const float* __restrict__ e_dst,
    float* __restrict__ alpha, int n_edges) {
  int e = blockIdx.x * 256 + threadIdx.x;
  if (e >= n_edges) return;
  int s = src[e], d = dst[e];
  float4 es = ((const float4*)e_src)[s];
  float4 ed = ((const float4*)e_dst)[d];
  float v[4] = {es.x + ed.x, es.y + ed.y, es.z + ed.z, es.w + ed.w};
  float m = -1e30f;
#pragma unroll
  for (int i = 0; i < 4; ++i) {
    v[i] = (v[i] > 0.f) ? v[i] : NEG_SLOPE * v[i];
    m = fmaxf(m, v[i]);
  }
  float sum = 0.f;
#pragma unroll
  for (int i = 0; i < 4; ++i) {
    v[i] = __expf(v[i] - m);
    sum += v[i];
  }
  float inv = 1.f / sum;
  ((float4*)alpha)[e] = make_float4(v[0] * inv, v[1] * inv, v[2] * inv, v[3] * inv);
}

// ---------------------------------------------------------------------------
// Kernel 3: scatter — one lane per (edge, feature c in 0..63).
// 64 consecutive lanes of a wave share one edge: coalesced h[src] read,
// atomicAdd into out[dst] (device-scope, XCD-safe).
// ---------------------------------------------------------------------------
__global__ __launch_bounds__(256) void k_scatter(
    const int* __restrict__ src, const int* __restrict__ dst,
    const float* __restrict__ h, const float* __restrict__ alpha,
    float* __restrict__ out, int n_edges) {
  long gid = (long)blockIdx.x * 256 + threadIdx.x;
  int c = (int)(gid & 63);
  long e = gid >> 6;
  if (e >= n_edges) return;
  int s = src[e], d = dst[e];
  float al = alpha[e * N_HEADS + (c >> 4)];
  float hv = h[(size_t)s * HF + c];
  atomicAdd(&out[(size_t)d * HF + c], al * hv);
}

extern "C" void kernel_launch(void* const* d_in, const int* in_sizes, int n_in,
                              void* d_out, int out_size, void* d_ws, size_t ws_size,
                              hipStream_t stream) {
  const float* x = (const float*)d_in[0];
  const int* ei = (const int*)d_in[1];
  const float* W = (const float*)d_in[2];
  const float* a = (const float*)d_in[3];
  float* out = (float*)d_out;

  const int n_nodes = in_sizes[0] / IN_FEAT;   // 50000
  const int n_edges = in_sizes[1] / 2;         // 800000
  const int* src = ei;
  const int* dst = ei + n_edges;

  // Workspace layout (all 16B-aligned):
  char* ws = (char*)d_ws;
  float* h = (float*)ws;                                      // 12.8 MB
  float* e_src = (float*)(ws + (size_t)n_nodes * HF * 4);     // 0.8 MB
  float* e_dst = e_src + (size_t)n_nodes * N_HEADS;           // 0.8 MB
  float* alpha = e_dst + (size_t)n_nodes * N_HEADS;           // 12.8 MB

  // out is re-poisoned before every timed launch -> zero it (graph-capturable).
  hipMemsetAsync(d_out, 0, (size_t)out_size * sizeof(float), stream);

  k_gemm<<<(n_nodes + 15) / 16, 256, 0, stream>>>(x, W, a, h, e_src, e_dst, n_nodes);
  k_alpha<<<(n_edges + 255) / 256, 256, 0, stream>>>(src, dst, e_src, e_dst, alpha, n_edges);
  long total = (long)n_edges * 64;
  k_scatter<<<(int)((total + 255) / 256), 256, 0, stream>>>(src, dst, h, alpha, out, n_edges);
}

// Round 2
// 307.479 us; speedup vs baseline: 1.0160x; 1.0160x over previous
//
#include <hip/hip_runtime.h>
#include <hip/hip_bf16.h>

#define IN_FEAT 128
#define N_HEADS 4
#define OUT_FEAT 16
#define HF 64  // N_HEADS * OUT_FEAT
#define NEG_SLOPE 0.2f

// ---------------------------------------------------------------------------
// Kernel 1: h = x @ W  (50000x128 @ 128x64), fused e_src/e_dst reductions.
// One block handles 16 nodes. LDS: W 32KB + x-tile 8KB + h-tile 4KB = 44KB.
// ---------------------------------------------------------------------------
__global__ __launch_bounds__(256) void k_gemm(
    const float* __restrict__ x, const float* __restrict__ W,
    const float* __restrict__ a, float* __restrict__ h,
    float* __restrict__ e_src, float* __restrict__ e_dst, int n_nodes) {
  __shared__ float sW[IN_FEAT][HF];   // W[k][c]
  __shared__ float sx[16][IN_FEAT];
  __shared__ float sh[16][HF];
  const int t = threadIdx.x;
  const int nb = blockIdx.x * 16;

  for (int i = t; i < IN_FEAT * HF; i += 256) sW[i >> 6][i & 63] = W[i];
  for (int i = t; i < 16 * IN_FEAT; i += 256) {
    int n = i >> 7, k = i & 127;
    int gn = nb + n;
    sx[n][k] = (gn < n_nodes) ? x[(size_t)gn * IN_FEAT + k] : 0.f;
  }
  __syncthreads();

  const int c = t & 63, n0 = t >> 6;
  for (int rep = 0; rep < 4; ++rep) {
    int n = n0 + rep * 4;
    float acc = 0.f;
#pragma unroll
    for (int k = 0; k < IN_FEAT; ++k) acc = fmaf(sx[n][k], sW[k][c], acc);
    sh[n][c] = acc;
    int gn = nb + n;
    if (gn < n_nodes) h[(size_t)gn * HF + c] = acc;
  }
  __syncthreads();

  if (t < 64) {
    int n = t >> 2, hd = t & 3;
    int gn = nb + n;
    if (gn < n_nodes) {
      float es = 0.f, ed = 0.f;
#pragma unroll
      for (int f = 0; f < OUT_FEAT; ++f) {
        float hv = sh[n][hd * OUT_FEAT + f];
        es = fmaf(hv, a[hd * 2 * OUT_FEAT + f], es);
        ed = fmaf(hv, a[hd * 2 * OUT_FEAT + OUT_FEAT + f], ed);
      }
      e_src[gn * N_HEADS + hd] = es;
      e_dst[gn * N_HEADS + hd] = ed;
    }
  }
}

// ---------------------------------------------------------------------------
// Kernel 2: per-edge leaky-relu + softmax over 4 heads -> alpha[e][4]
// ---------------------------------------------------------------------------
__global__ __launch_bounds__(256) void k_alpha(
    const int* __restrict__ src, const int* __restrict__ dst,
    const float* __restrict__ e_src, const float* __restrict__ e_dst,
    float* __restrict__ alpha, int n_edges) {
  int e = blockIdx.x * 256 + threadIdx.x;
  if (e >= n_edges) return;
  int s = src[e], d = dst[e];
  float4 es = ((const float4*)e_src)[s];
  float4 ed = ((const float4*)e_dst)[d];
  float v[4] = {es.x + ed.x, es.y + ed.y, es.z + ed.z, es.w + ed.w};
  float m = -1e30f;
#pragma unroll
  for (int i = 0; i < 4; ++i) {
    v[i] = (v[i] > 0.f) ? v[i] : NEG_SLOPE * v[i];
    m = fmaxf(m, v[i]);
  }
  float sum = 0.f;
#pragma unroll
  for (int i = 0; i < 4; ++i) {
    v[i] = __expf(v[i] - m);
    sum += v[i];
  }
  float inv = 1.f / sum;
  ((float4*)alpha)[e] = make_float4(v[0] * inv, v[1] * inv, v[2] * inv, v[3] * inv);
}

// ---------------------------------------------------------------------------
// CSR build: histogram -> 2-level exclusive scan -> reorder (src + alpha)
// ---------------------------------------------------------------------------
__global__ __launch_bounds__(256) void k_hist(
    const int* __restrict__ dst, int* __restrict__ counts, int n_edges) {
  int e = blockIdx.x * 256 + threadIdx.x;
  if (e < n_edges) atomicAdd(&counts[dst[e]], 1);
}

// pass 1: per-256-tile sums
__global__ __launch_bounds__(256) void k_scan1(
    const int* __restrict__ counts, int* __restrict__ partial, int n) {
  __shared__ int s[256];
  int t = threadIdx.x;
  int i = blockIdx.x * 256 + t;
  s[t] = (i < n) ? counts[i] : 0;
  __syncthreads();
  for (int off = 128; off > 0; off >>= 1) {
    if (t < off) s[t] += s[t + off];
    __syncthreads();
  }
  if (t == 0) partial[blockIdx.x] = s[0];
}

// pass 2: single-block exclusive scan of tile sums (nb <= 256)
__global__ __launch_bounds__(256) void k_scan2(int* __restrict__ partial, int nb) {
  __shared__ int s[256];
  int t = threadIdx.x;
  s[t] = (t < nb) ? partial[t] : 0;
  __syncthreads();
  for (int off = 1; off < 256; off <<= 1) {
    int v = (t >= off) ? s[t - off] : 0;
    __syncthreads();
    s[t] += v;
    __syncthreads();
  }
  if (t < nb) partial[t] = (t == 0) ? 0 : s[t - 1];
}

// pass 3: per-tile exclusive scan + tile prefix -> offsets & cursor
__global__ __launch_bounds__(256) void k_scan3(
    const int* __restrict__ counts, const int* __restrict__ partial,
    int* __restrict__ offsets, int* __restrict__ cursor, int n, int n_edges) {
  __shared__ int s[256];
  int t = threadIdx.x;
  int i = blockIdx.x * 256 + t;
  int v = (i < n) ? counts[i] : 0;
  s[t] = v;
  __syncthreads();
  for (int off = 1; off < 256; off <<= 1) {
    int u = (t >= off) ? s[t - off] : 0;
    __syncthreads();
    s[t] += u;
    __syncthreads();
  }
  int excl = s[t] - v + partial[blockIdx.x];
  if (i < n) {
    offsets[i] = excl;
    cursor[i] = excl;
  }
  if (i == 0) offsets[n] = n_edges;
}

__global__ __launch_bounds__(256) void k_reorder(
    const int* __restrict__ src, const int* __restrict__ dst,
    const float* __restrict__ alpha, int* __restrict__ cursor,
    int* __restrict__ sorted_src, float* __restrict__ sorted_alpha, int n_edges) {
  int e = blockIdx.x * 256 + threadIdx.x;
  if (e >= n_edges) return;
  int d = dst[e];
  int pos = atomicAdd(&cursor[d], 1);
  sorted_src[pos] = src[e];
  ((float4*)sorted_alpha)[pos] = ((const float4*)alpha)[e];
}

// ---------------------------------------------------------------------------
// Gather: one wave per destination node, lane = output feature.
// Sequential accumulation over the node's CSR segment; one coalesced store.
// No atomics; every node (incl. degree-0) writes -> no out memset needed.
// ---------------------------------------------------------------------------
__global__ __launch_bounds__(256) void k_gather(
    const int* __restrict__ sorted_src, const float* __restrict__ sorted_alpha,
    const int* __restrict__ offsets, const float* __restrict__ h,
    float* __restrict__ out, int n_nodes) {
  int gid = blockIdx.x * 256 + threadIdx.x;
  int d = gid >> 6;         // node = wave
  int c = gid & 63;         // feature = lane
  if (d >= n_nodes) return;
  int beg = offsets[d];
  int end = offsets[d + 1];
  int hd = c >> 4;
  float acc = 0.f;
  for (int j = beg; j < end; ++j) {
    int s = sorted_src[j];
    float al = sorted_alpha[(size_t)j * 4 + hd];  // all lanes within 16B line
    acc = fmaf(al, h[(size_t)s * HF + c], acc);
  }
  out[(size_t)d * HF + c] = acc;
}

extern "C" void kernel_launch(void* const* d_in, const int* in_sizes, int n_in,
                              void* d_out, int out_size, void* d_ws, size_t ws_size,
                              hipStream_t stream) {
  const float* x = (const float*)d_in[0];
  const int* ei = (const int*)d_in[1];
  const float* W = (const float*)d_in[2];
  const float* a = (const float*)d_in[3];
  float* out = (float*)d_out;

  const int n_nodes = in_sizes[0] / IN_FEAT;   // 50000
  const int n_edges = in_sizes[1] / 2;         // 800000
  const int* src = ei;
  const int* dst = ei + n_edges;

  // Workspace layout (16B-aligned chunks):
  char* ws = (char*)d_ws;
  size_t off = 0;
  float* h = (float*)(ws + off);            off += (size_t)n_nodes * HF * 4;        // 12.8 MB
  float* alpha = (float*)(ws + off);        off += (size_t)n_edges * N_HEADS * 4;   // 12.8 MB
  float* sorted_alpha = (float*)(ws + off); off += (size_t)n_edges * N_HEADS * 4;   // 12.8 MB
  float* e_src = (float*)(ws + off);        off += (size_t)n_nodes * N_HEADS * 4;   // 0.8 MB
  float* e_dst = (float*)(ws + off);        off += (size_t)n_nodes * N_HEADS * 4;   // 0.8 MB
  int* sorted_src = (int*)(ws + off);       off += (size_t)n_edges * 4;             // 3.2 MB
  int* counts = (int*)(ws + off);           off += ((size_t)n_nodes + 4) * 4;
  int* offsets = (int*)(ws + off);          off += ((size_t)n_nodes + 4) * 4;
  int* cursor = (int*)(ws + off);           off += ((size_t)n_nodes + 4) * 4;
  int* partial = (int*)(ws + off);          off += 256 * 4;

  const int nb_nodes = (n_nodes + 255) / 256;  // 196 (<=256 required by k_scan2)
  const int nb_edges = (n_edges + 255) / 256;

  hipMemsetAsync(counts, 0, (size_t)n_nodes * 4, stream);

  k_gemm<<<(n_nodes + 15) / 16, 256, 0, stream>>>(x, W, a, h, e_src, e_dst, n_nodes);
  k_hist<<<nb_edges, 256, 0, stream>>>(dst, counts, n_edges);
  k_alpha<<<nb_edges, 256, 0, stream>>>(src, dst, e_src, e_dst, alpha, n_edges);
  k_scan1<<<nb_nodes, 256, 0, stream>>>(counts, partial, n_nodes);
  k_scan2<<<1, 256, 0, stream>>>(partial, nb_nodes);
  k_scan3<<<nb_nodes, 256, 0, stream>>>(counts, partial, offsets, cursor, n_nodes, n_edges);
  k_reorder<<<nb_edges, 256, 0, stream>>>(src, dst, alpha, cursor, sorted_src, sorted_alpha, n_edges);
  k_gather<<<(n_nodes * 64 + 255) / 256, 256, 0, stream>>>(
      sorted_src, sorted_alpha, offsets, h, out, n_nodes);
}

// Round 3
// 276.190 us; speedup vs baseline: 1.1312x; 1.1133x over previous
//
#include <hip/hip_runtime.h>
#include <hip/hip_bf16.h>

#define IN_FEAT 128
#define N_HEADS 4
#define OUT_FEAT 16
#define HF 64  // N_HEADS * OUT_FEAT
#define NEG_SLOPE 0.2f

typedef __hip_bfloat16 bf16;

// ---------------------------------------------------------------------------
// Kernel 1: h = x @ W (50000x128 @ 128x64), register-tiled, fp32 math.
// Block = 256 threads = 64 nodes. Thread owns 4 nodes x 4 cols (one per head).
// LDS: W as float4 k-chunks [32][64] (32KB), x tile [64][33] float4 padded
// (33.8KB), h tile bf16 [64][68] padded (8.7KB) -> 74.5KB -> 2 blocks/CU.
// Outputs: h_bf16 (for gather), e_src/e_dst fp32.
// ---------------------------------------------------------------------------
__global__ __launch_bounds__(256) void k_gemm(
    const float* __restrict__ x, const float* __restrict__ W,
    const float* __restrict__ a, bf16* __restrict__ h16,
    float* __restrict__ e_src, float* __restrict__ e_dst, int n_nodes) {
  __shared__ float4 sW4[32 * 64];      // sW4[k4*64+c] = {W[4k4..4k4+3][c]}
  __shared__ float4 sx4[64 * 33];      // sx4[n*33+k4] = x[node][4k4..4k4+3]
  __shared__ bf16 sh[64 * 68];         // h tile, row stride 68
  const int t = threadIdx.x;
  const int nb = blockIdx.x * 64;

  // Stage W transposed into float4 k-chunks.
  float* sW4f = (float*)sW4;
  for (int i = t; i < IN_FEAT * HF; i += 256) {
    int k = i >> 6, c = i & 63;
    sW4f[(((k >> 2) * 64) + c) * 4 + (k & 3)] = W[i];
  }
  // Stage x tile (64 nodes x 32 float4) — coalesced global reads.
  const float4* x4 = (const float4*)x;
  for (int i = t; i < 64 * 32; i += 256) {
    int n = i >> 5, k4 = i & 31;
    int gn = nb + n;
    sx4[n * 33 + k4] =
        (gn < n_nodes) ? x4[(size_t)gn * 32 + k4] : make_float4(0.f, 0.f, 0.f, 0.f);
  }
  __syncthreads();

  const int c0 = t & 15;   // feature within head
  const int g = t >> 4;    // node group (4 nodes each)
  float acc[4][4];         // [r][hd]
#pragma unroll
  for (int r = 0; r < 4; ++r)
#pragma unroll
    for (int hd = 0; hd < 4; ++hd) acc[r][hd] = 0.f;

  for (int k4 = 0; k4 < 32; ++k4) {
    float4 wv[4], xv[4];
#pragma unroll
    for (int hd = 0; hd < 4; ++hd) wv[hd] = sW4[k4 * 64 + hd * 16 + c0];
#pragma unroll
    for (int r = 0; r < 4; ++r) xv[r] = sx4[(g * 4 + r) * 33 + k4];
#pragma unroll
    for (int r = 0; r < 4; ++r)
#pragma unroll
      for (int hd = 0; hd < 4; ++hd) {
        acc[r][hd] = fmaf(xv[r].x, wv[hd].x, acc[r][hd]);
        acc[r][hd] = fmaf(xv[r].y, wv[hd].y, acc[r][hd]);
        acc[r][hd] = fmaf(xv[r].z, wv[hd].z, acc[r][hd]);
        acc[r][hd] = fmaf(xv[r].w, wv[hd].w, acc[r][hd]);
      }
  }

  // Write h tile to LDS as bf16.
#pragma unroll
  for (int r = 0; r < 4; ++r)
#pragma unroll
    for (int hd = 0; hd < 4; ++hd)
      sh[(g * 4 + r) * 68 + hd * 16 + c0] = __float2bfloat16(acc[r][hd]);
  __syncthreads();

  // e_src/e_dst: 64 nodes x 4 heads = 256 entries, one per thread.
  {
    int n = t >> 2, hd = t & 3;
    int gn = nb + n;
    if (gn < n_nodes) {
      float es = 0.f, ed = 0.f;
#pragma unroll
      for (int f = 0; f < OUT_FEAT; ++f) {
        float hv = __bfloat162float(sh[n * 68 + hd * 16 + f]);
        es = fmaf(hv, a[hd * 2 * OUT_FEAT + f], es);
        ed = fmaf(hv, a[hd * 2 * OUT_FEAT + OUT_FEAT + f], ed);
      }
      e_src[gn * N_HEADS + hd] = es;
      e_dst[gn * N_HEADS + hd] = ed;
    }
  }

  // Write h16 to global: ushort4 (8B) per store, coalesced.
  for (int i = t; i < 64 * 16; i += 256) {
    int n = i >> 4, c4 = (i & 15) * 4;
    int gn = nb + n;
    if (gn < n_nodes) {
      ushort4 v;
      v.x = *(const unsigned short*)&sh[n * 68 + c4 + 0];
      v.y = *(const unsigned short*)&sh[n * 68 + c4 + 1];
      v.z = *(const unsigned short*)&sh[n * 68 + c4 + 2];
      v.w = *(const unsigned short*)&sh[n * 68 + c4 + 3];
      *(ushort4*)((unsigned short*)h16 + (size_t)gn * HF + c4) = v;
    }
  }
}

// ---------------------------------------------------------------------------
// CSR build: histogram -> 2-level exclusive scan -> reorder (src+dst only)
// ---------------------------------------------------------------------------
__global__ __launch_bounds__(256) void k_hist(
    const int* __restrict__ dst, int* __restrict__ counts, int n_edges) {
  int e = blockIdx.x * 256 + threadIdx.x;
  if (e < n_edges) atomicAdd(&counts[dst[e]], 1);
}

__global__ __launch_bounds__(256) void k_scan1(
    const int* __restrict__ counts, int* __restrict__ partial, int n) {
  __shared__ int s[256];
  int t = threadIdx.x;
  int i = blockIdx.x * 256 + t;
  s[t] = (i < n) ? counts[i] : 0;
  __syncthreads();
  for (int off = 128; off > 0; off >>= 1) {
    if (t < off) s[t] += s[t + off];
    __syncthreads();
  }
  if (t == 0) partial[blockIdx.x] = s[0];
}

__global__ __launch_bounds__(256) void k_scan2(int* __restrict__ partial, int nb) {
  __shared__ int s[256];
  int t = threadIdx.x;
  s[t] = (t < nb) ? partial[t] : 0;
  __syncthreads();
  for (int off = 1; off < 256; off <<= 1) {
    int v = (t >= off) ? s[t - off] : 0;
    __syncthreads();
    s[t] += v;
    __syncthreads();
  }
  if (t < nb) partial[t] = (t == 0) ? 0 : s[t - 1];
}

__global__ __launch_bounds__(256) void k_scan3(
    const int* __restrict__ counts, const int* __restrict__ partial,
    int* __restrict__ offsets, int* __restrict__ cursor, int n, int n_edges) {
  __shared__ int s[256];
  int t = threadIdx.x;
  int i = blockIdx.x * 256 + t;
  int v = (i < n) ? counts[i] : 0;
  s[t] = v;
  __syncthreads();
  for (int off = 1; off < 256; off <<= 1) {
    int u = (t >= off) ? s[t - off] : 0;
    __syncthreads();
    s[t] += u;
    __syncthreads();
  }
  int excl = s[t] - v + partial[blockIdx.x];
  if (i < n) {
    offsets[i] = excl;
    cursor[i] = excl;
  }
  if (i == 0) offsets[n] = n_edges;
}

__global__ __launch_bounds__(256) void k_reorder(
    const int* __restrict__ src, const int* __restrict__ dst,
    int* __restrict__ cursor, int* __restrict__ sorted_src,
    int* __restrict__ sorted_dst, int n_edges) {
  int e = blockIdx.x * 256 + threadIdx.x;
  if (e >= n_edges) return;
  int d = dst[e];
  int pos = atomicAdd(&cursor[d], 1);
  sorted_src[pos] = src[e];
  sorted_dst[pos] = d;
}

// ---------------------------------------------------------------------------
// alpha over SORTED edges: streamed reads of sorted_src/sorted_dst, gathered
// 16B e-table reads (L2-resident), fully COALESCED float4 alpha writes.
// ---------------------------------------------------------------------------
__global__ __launch_bounds__(256) void k_alpha2(
    const int* __restrict__ sorted_src, const int* __restrict__ sorted_dst,
    const float* __restrict__ e_src, const float* __restrict__ e_dst,
    float* __restrict__ alpha, int n_edges) {
  int e = blockIdx.x * 256 + threadIdx.x;
  if (e >= n_edges) return;
  int s = sorted_src[e], d = sorted_dst[e];
  float4 es = ((const float4*)e_src)[s];
  float4 ed = ((const float4*)e_dst)[d];
  float v[4] = {es.x + ed.x, es.y + ed.y, es.z + ed.z, es.w + ed.w};
  float m = -1e30f;
#pragma unroll
  for (int i = 0; i < 4; ++i) {
    v[i] = (v[i] > 0.f) ? v[i] : NEG_SLOPE * v[i];
    m = fmaxf(m, v[i]);
  }
  float sum = 0.f;
#pragma unroll
  for (int i = 0; i < 4; ++i) {
    v[i] = __expf(v[i] - m);
    sum += v[i];
  }
  float inv = 1.f / sum;
  ((float4*)alpha)[e] = make_float4(v[0] * inv, v[1] * inv, v[2] * inv, v[3] * inv);
}

// ---------------------------------------------------------------------------
// Gather: one wave per destination node, lane = feature. bf16 h (128B/edge).
// ---------------------------------------------------------------------------
__global__ __launch_bounds__(256) void k_gather(
    const int* __restrict__ sorted_src, const float* __restrict__ sorted_alpha,
    const int* __restrict__ offsets, const bf16* __restrict__ h16,
    float* __restrict__ out, int n_nodes) {
  int gid = blockIdx.x * 256 + threadIdx.x;
  int d = gid >> 6;
  int c = gid & 63;
  if (d >= n_nodes) return;
  int beg = offsets[d];
  int end = offsets[d + 1];
  int hd = c >> 4;
  float acc = 0.f;
  for (int j = beg; j < end; ++j) {
    int s = sorted_src[j];
    float al = sorted_alpha[(size_t)j * 4 + hd];
    acc = fmaf(al, __bfloat162float(h16[(size_t)s * HF + c]), acc);
  }
  out[(size_t)d * HF + c] = acc;
}

extern "C" void kernel_launch(void* const* d_in, const int* in_sizes, int n_in,
                              void* d_out, int out_size, void* d_ws, size_t ws_size,
                              hipStream_t stream) {
  const float* x = (const float*)d_in[0];
  const int* ei = (const int*)d_in[1];
  const float* W = (const float*)d_in[2];
  const float* a = (const float*)d_in[3];
  float* out = (float*)d_out;

  const int n_nodes = in_sizes[0] / IN_FEAT;   // 50000
  const int n_edges = in_sizes[1] / 2;         // 800000
  const int* src = ei;
  const int* dst = ei + n_edges;

  char* ws = (char*)d_ws;
  size_t off = 0;
  bf16* h16 = (bf16*)(ws + off);          off += (size_t)n_nodes * HF * 2;        // 6.4 MB
  float* alpha = (float*)(ws + off);      off += (size_t)n_edges * N_HEADS * 4;   // 12.8 MB
  float* e_src = (float*)(ws + off);      off += (size_t)n_nodes * N_HEADS * 4;   // 0.8 MB
  float* e_dst = (float*)(ws + off);      off += (size_t)n_nodes * N_HEADS * 4;   // 0.8 MB
  int* sorted_src = (int*)(ws + off);     off += (size_t)n_edges * 4;             // 3.2 MB
  int* sorted_dst = (int*)(ws + off);     off += (size_t)n_edges * 4;             // 3.2 MB
  int* counts = (int*)(ws + off);         off += ((size_t)n_nodes + 4) * 4;
  int* offsets = (int*)(ws + off);        off += ((size_t)n_nodes + 4) * 4;
  int* cursor = (int*)(ws + off);         off += ((size_t)n_nodes + 4) * 4;
  int* partial = (int*)(ws + off);        off += 256 * 4;

  const int nb_nodes = (n_nodes + 255) / 256;  // 196 <= 256 (k_scan2 limit)
  const int nb_edges = (n_edges + 255) / 256;

  hipMemsetAsync(counts, 0, (size_t)n_nodes * 4, stream);

  k_gemm<<<(n_nodes + 63) / 64, 256, 0, stream>>>(x, W, a, h16, e_src, e_dst, n_nodes);
  k_hist<<<nb_edges, 256, 0, stream>>>(dst, counts, n_edges);
  k_scan1<<<nb_nodes, 256, 0, stream>>>(counts, partial, n_nodes);
  k_scan2<<<1, 256, 0, stream>>>(partial, nb_nodes);
  k_scan3<<<nb_nodes, 256, 0, stream>>>(counts, partial, offsets, cursor, n_nodes, n_edges);
  k_reorder<<<nb_edges, 256, 0, stream>>>(src, dst, cursor, sorted_src, sorted_dst, n_edges);
  k_alpha2<<<nb_edges, 256, 0, stream>>>(sorted_src, sorted_dst, e_src, e_dst, alpha, n_edges);
  k_gather<<<(n_nodes * 64 + 255) / 256, 256, 0, stream>>>(
      sorted_src, alpha, offsets, h16, out, n_nodes);
}

// Round 4
// 252.340 us; speedup vs baseline: 1.2381x; 1.0945x over previous
//
#include <hip/hip_runtime.h>
#include <hip/hip_bf16.h>

#define IN_FEAT 128
#define N_HEADS 4
#define OUT_FEAT 16
#define HF 64  // N_HEADS * OUT_FEAT
#define NEG_SLOPE 0.2f

typedef __hip_bfloat16 bf16;
typedef __attribute__((ext_vector_type(8))) short short8;
typedef __attribute__((ext_vector_type(4))) float f32x4;

__device__ inline unsigned short f2b(float f) {
  bf16 b = __float2bfloat16(f);
  return *(unsigned short*)&b;
}
__device__ inline float b2f(unsigned short u) {
  return __uint_as_float((unsigned)u << 16);
}

// ---------------------------------------------------------------------------
// Kernel 1: h = x @ W via bf16 MFMA. Block = 256 thr = 4 waves = 64 nodes.
// Wave w owns nodes [w*16,w*16+16) x all 64 cols = 4 mfma 16x16 n-tiles,
// K=128 in 4 chunks of 32 -> 16 mfma_f32_16x16x32_bf16 per wave.
// LDS: xs[64][136] bf16 (pad 136 -> conflict-free b128 frag reads),
//      wt[64][136] (W transposed), sh[64][68] h-tile. 43.5 KB -> 3 blk/CU.
// Fragment layouts (m89/m120): A[m=lane&15][k=(lane>>4)*8+j],
// B[k=(lane>>4)*8+j][n=lane&15], D col=lane&15 row=(lane>>4)*4+reg.
// ---------------------------------------------------------------------------
__global__ __launch_bounds__(256) void k_gemm(
    const float* __restrict__ x, const float* __restrict__ W,
    const float* __restrict__ a, unsigned short* __restrict__ h16,
    float* __restrict__ e_src, float* __restrict__ e_dst, int n_nodes) {
  __shared__ unsigned short xs[64][136];
  __shared__ unsigned short wt[64][136];
  __shared__ unsigned short sh[64][68];
  const int t = threadIdx.x;
  const int nb = blockIdx.x * 64;
  const int lane = t & 63;
  const int w = t >> 6;

  // Stage x tile (fp32 -> bf16), coalesced float4 reads, ushort4 LDS writes.
  const float4* x4 = (const float4*)x;
  for (int i = t; i < 64 * 32; i += 256) {
    int n = i >> 5, k4 = i & 31;
    int gn = nb + n;
    float4 v = (gn < n_nodes) ? x4[(size_t)gn * 32 + k4]
                              : make_float4(0.f, 0.f, 0.f, 0.f);
    ushort4 u;
    u.x = f2b(v.x); u.y = f2b(v.y); u.z = f2b(v.z); u.w = f2b(v.w);
    *(ushort4*)&xs[n][k4 * 4] = u;
  }
  // Stage W transposed (fp32 -> bf16): coalesced reads, scalar LDS writes.
  for (int i = t; i < IN_FEAT * HF; i += 256) {
    int k = i >> 6, c = i & 63;
    wt[c][k] = f2b(W[i]);
  }
  __syncthreads();

  const int m = lane & 15;
  const int q = lane >> 4;
  f32x4 acc[4];
#pragma unroll
  for (int nt = 0; nt < 4; ++nt) acc[nt] = (f32x4){0.f, 0.f, 0.f, 0.f};

#pragma unroll
  for (int kc = 0; kc < 4; ++kc) {
    short8 af = *(const short8*)&xs[w * 16 + m][kc * 32 + q * 8];
#pragma unroll
    for (int nt = 0; nt < 4; ++nt) {
      short8 bfr = *(const short8*)&wt[nt * 16 + m][kc * 32 + q * 8];
      acc[nt] = __builtin_amdgcn_mfma_f32_16x16x32_bf16(af, bfr, acc[nt], 0, 0, 0);
    }
  }

  // D -> sh tile (bf16).
#pragma unroll
  for (int nt = 0; nt < 4; ++nt)
#pragma unroll
    for (int r = 0; r < 4; ++r)
      sh[w * 16 + q * 4 + r][nt * 16 + m] = f2b(acc[nt][r]);
  __syncthreads();

  // e_src/e_dst: 64 nodes x 4 heads, one per thread.
  {
    int n = t >> 2, hd = t & 3;
    int gn = nb + n;
    if (gn < n_nodes) {
      float es = 0.f, ed = 0.f;
#pragma unroll
      for (int f = 0; f < OUT_FEAT; ++f) {
        float hv = b2f(sh[n][hd * 16 + f]);
        es = fmaf(hv, a[hd * 2 * OUT_FEAT + f], es);
        ed = fmaf(hv, a[hd * 2 * OUT_FEAT + OUT_FEAT + f], ed);
      }
      e_src[gn * N_HEADS + hd] = es;
      e_dst[gn * N_HEADS + hd] = ed;
    }
  }

  // h16 global write, ushort4 coalesced.
  for (int i = t; i < 64 * 16; i += 256) {
    int n = i >> 4, c4 = (i & 15) * 4;
    int gn = nb + n;
    if (gn < n_nodes) {
      ushort4 v;
      v.x = sh[n][c4 + 0]; v.y = sh[n][c4 + 1];
      v.z = sh[n][c4 + 2]; v.w = sh[n][c4 + 3];
      *(ushort4*)(h16 + (size_t)gn * HF + c4) = v;
    }
  }
}

// ---------------------------------------------------------------------------
// CSR build: histogram -> 2-level scan -> reorder (sorted_src ONLY)
// ---------------------------------------------------------------------------
__global__ __launch_bounds__(256) void k_hist(
    const int* __restrict__ dst, int* __restrict__ counts, int n_edges) {
  int e = blockIdx.x * 256 + threadIdx.x;
  if (e < n_edges) atomicAdd(&counts[dst[e]], 1);
}

__global__ __launch_bounds__(256) void k_scan1(
    const int* __restrict__ counts, int* __restrict__ partial, int n) {
  __shared__ int s[256];
  int t = threadIdx.x;
  int i = blockIdx.x * 256 + t;
  s[t] = (i < n) ? counts[i] : 0;
  __syncthreads();
  for (int off = 128; off > 0; off >>= 1) {
    if (t < off) s[t] += s[t + off];
    __syncthreads();
  }
  if (t == 0) partial[blockIdx.x] = s[0];
}

__global__ __launch_bounds__(256) void k_scan2(int* __restrict__ partial, int nb) {
  __shared__ int s[256];
  int t = threadIdx.x;
  s[t] = (t < nb) ? partial[t] : 0;
  __syncthreads();
  for (int off = 1; off < 256; off <<= 1) {
    int v = (t >= off) ? s[t - off] : 0;
    __syncthreads();
    s[t] += v;
    __syncthreads();
  }
  if (t < nb) partial[t] = (t == 0) ? 0 : s[t - 1];
}

__global__ __launch_bounds__(256) void k_scan3(
    const int* __restrict__ counts, const int* __restrict__ partial,
    int* __restrict__ offsets, int* __restrict__ cursor, int n, int n_edges) {
  __shared__ int s[256];
  int t = threadIdx.x;
  int i = blockIdx.x * 256 + t;
  int v = (i < n) ? counts[i] : 0;
  s[t] = v;
  __syncthreads();
  for (int off = 1; off < 256; off <<= 1) {
    int u = (t >= off) ? s[t - off] : 0;
    __syncthreads();
    s[t] += u;
    __syncthreads();
  }
  int excl = s[t] - v + partial[blockIdx.x];
  if (i < n) {
    offsets[i] = excl;
    cursor[i] = excl;
  }
  if (i == 0) offsets[n] = n_edges;
}

__global__ __launch_bounds__(256) void k_reorder(
    const int* __restrict__ src, const int* __restrict__ dst,
    int* __restrict__ cursor, int* __restrict__ sorted_src, int n_edges) {
  int e = blockIdx.x * 256 + threadIdx.x;
  if (e >= n_edges) return;
  int d = dst[e];
  int pos = atomicAdd(&cursor[d], 1);
  sorted_src[pos] = src[e];
}

// ---------------------------------------------------------------------------
// Fused softmax + gather: one wave per dst node, lane = feature.
// Per edge: s (broadcast, scalarized), e_src[s] 16B (L2-resident), 4-head
// softmax recomputed per-lane (VALU, overlapped), h16[s] 128B gather.
// Unroll x4 -> 4 independent load chains to break the latency chain.
// ---------------------------------------------------------------------------
__device__ inline float alpha_of(const float4 es, const float4 ed, int hd) {
  float v0 = es.x + ed.x, v1 = es.y + ed.y, v2 = es.z + ed.z, v3 = es.w + ed.w;
  v0 = (v0 > 0.f) ? v0 : NEG_SLOPE * v0;
  v1 = (v1 > 0.f) ? v1 : NEG_SLOPE * v1;
  v2 = (v2 > 0.f) ? v2 : NEG_SLOPE * v2;
  v3 = (v3 > 0.f) ? v3 : NEG_SLOPE * v3;
  float m = fmaxf(fmaxf(v0, v1), fmaxf(v2, v3));
  float e0 = __expf(v0 - m), e1 = __expf(v1 - m);
  float e2 = __expf(v2 - m), e3 = __expf(v3 - m);
  float sum = e0 + e1 + e2 + e3;
  float num = (hd == 0) ? e0 : (hd == 1) ? e1 : (hd == 2) ? e2 : e3;
  return num / sum;
}

__global__ __launch_bounds__(256) void k_gather(
    const int* __restrict__ sorted_src, const int* __restrict__ offsets,
    const float* __restrict__ e_src, const float* __restrict__ e_dst,
    const unsigned short* __restrict__ h16, float* __restrict__ out,
    int n_nodes) {
  int gid = blockIdx.x * 256 + threadIdx.x;
  int d = gid >> 6;
  int c = gid & 63;
  if (d >= n_nodes) return;
  int beg = offsets[d];
  int end = offsets[d + 1];
  int hd = c >> 4;
  float4 ed = ((const float4*)e_dst)[d];
  float acc = 0.f;
  int j = beg;
  for (; j + 4 <= end; j += 4) {
    int s0 = __builtin_amdgcn_readfirstlane(sorted_src[j + 0]);
    int s1 = __builtin_amdgcn_readfirstlane(sorted_src[j + 1]);
    int s2 = __builtin_amdgcn_readfirstlane(sorted_src[j + 2]);
    int s3 = __builtin_amdgcn_readfirstlane(sorted_src[j + 3]);
    float4 es0 = ((const float4*)e_src)[s0];
    float4 es1 = ((const float4*)e_src)[s1];
    float4 es2 = ((const float4*)e_src)[s2];
    float4 es3 = ((const float4*)e_src)[s3];
    float h0 = b2f(h16[(size_t)s0 * HF + c]);
    float h1 = b2f(h16[(size_t)s1 * HF + c]);
    float h2 = b2f(h16[(size_t)s2 * HF + c]);
    float h3 = b2f(h16[(size_t)s3 * HF + c]);
    acc = fmaf(alpha_of(es0, ed, hd), h0, acc);
    acc = fmaf(alpha_of(es1, ed, hd), h1, acc);
    acc = fmaf(alpha_of(es2, ed, hd), h2, acc);
    acc = fmaf(alpha_of(es3, ed, hd), h3, acc);
  }
  for (; j < end; ++j) {
    int s = __builtin_amdgcn_readfirstlane(sorted_src[j]);
    float4 es = ((const float4*)e_src)[s];
    float hv = b2f(h16[(size_t)s * HF + c]);
    acc = fmaf(alpha_of(es, ed, hd), hv, acc);
  }
  out[(size_t)d * HF + c] = acc;
}

extern "C" void kernel_launch(void* const* d_in, const int* in_sizes, int n_in,
                              void* d_out, int out_size, void* d_ws, size_t ws_size,
                              hipStream_t stream) {
  const float* x = (const float*)d_in[0];
  const int* ei = (const int*)d_in[1];
  const float* W = (const float*)d_in[2];
  const float* a = (const float*)d_in[3];
  float* out = (float*)d_out;

  const int n_nodes = in_sizes[0] / IN_FEAT;   // 50000
  const int n_edges = in_sizes[1] / 2;         // 800000
  const int* src = ei;
  const int* dst = ei + n_edges;

  char* ws = (char*)d_ws;
  size_t off = 0;
  unsigned short* h16 = (unsigned short*)(ws + off); off += (size_t)n_nodes * HF * 2;  // 6.4 MB
  float* e_src = (float*)(ws + off);      off += (size_t)n_nodes * N_HEADS * 4;        // 0.8 MB
  float* e_dst = (float*)(ws + off);      off += (size_t)n_nodes * N_HEADS * 4;        // 0.8 MB
  int* sorted_src = (int*)(ws + off);     off += (size_t)n_edges * 4;                  // 3.2 MB
  int* counts = (int*)(ws + off);         off += ((size_t)n_nodes + 4) * 4;
  int* offsets = (int*)(ws + off);        off += ((size_t)n_nodes + 4) * 4;
  int* cursor = (int*)(ws + off);         off += ((size_t)n_nodes + 4) * 4;
  int* partial = (int*)(ws + off);        off += 256 * 4;

  const int nb_nodes = (n_nodes + 255) / 256;  // 196 <= 256 (k_scan2 limit)
  const int nb_edges = (n_edges + 255) / 256;

  hipMemsetAsync(counts, 0, (size_t)n_nodes * 4, stream);

  k_gemm<<<(n_nodes + 63) / 64, 256, 0, stream>>>(x, W, a, h16, e_src, e_dst, n_nodes);
  k_hist<<<nb_edges, 256, 0, stream>>>(dst, counts, n_edges);
  k_scan1<<<nb_nodes, 256, 0, stream>>>(counts, partial, n_nodes);
  k_scan2<<<1, 256, 0, stream>>>(partial, nb_nodes);
  k_scan3<<<nb_nodes, 256, 0, stream>>>(counts, partial, offsets, cursor, n_nodes, n_edges);
  k_reorder<<<nb_edges, 256, 0, stream>>>(src, dst, cursor, sorted_src, n_edges);
  k_gather<<<(n_nodes * 64 + 255) / 256, 256, 0, stream>>>(
      sorted_src, offsets, e_src, e_dst, h16, out, n_nodes);
}